// Round 1
// baseline (40139.304 us; speedup 1.0000x reference)
//
#include <hip/hip_runtime.h>
#include <hip/hip_bf16.h>

// LSTM: L=1024, B=64, I=512, H=512, fp32 in/out.
// Persistent kernel: 8 clusters x 32 WGs. Cluster = 8 batches; WG = 16 h-idx
// (64 gate rows). Weights live in VGPRs as MFMA B-fragments. h exchanged via
// d_out itself (out[t] == h^{t+1}); per-cluster monotonic barrier in d_ws.

typedef __attribute__((ext_vector_type(8))) short bf16x8;
typedef __attribute__((ext_vector_type(4))) float f32x4;

#define NT 1024
#define NB 64
#define NH 512
#define NI 512

__device__ __forceinline__ bf16x8 pack8(float4 a, float4 b) {
    union U2 { __hip_bfloat162 h; unsigned int u; } c0, c1, c2, c3;
    c0.h = __float22bfloat162_rn(make_float2(a.x, a.y));
    c1.h = __float22bfloat162_rn(make_float2(a.z, a.w));
    c2.h = __float22bfloat162_rn(make_float2(b.x, b.y));
    c3.h = __float22bfloat162_rn(make_float2(b.z, b.w));
    union R { bf16x8 v; unsigned int u[4]; } r;
    r.u[0] = c0.u; r.u[1] = c1.u; r.u[2] = c2.u; r.u[3] = c3.u;
    return r.v;
}

__device__ __forceinline__ float sigm(float v) {
    return 1.0f / (1.0f + __expf(-v));
}
__device__ __forceinline__ float tanh_f(float v) {
    float e = __expf(-2.0f * fabsf(v));        // in (0,1], no overflow
    float r = (1.0f - e) / (1.0f + e);
    return copysignf(r, v);
}

__global__ __launch_bounds__(256, 1) void lstm_fused(
    const float* __restrict__ x,
    const float* __restrict__ h0,
    const float* __restrict__ c0,
    const float* __restrict__ Wf, const float* __restrict__ Bf,
    const float* __restrict__ Wi, const float* __restrict__ Bi,
    const float* __restrict__ Wc, const float* __restrict__ Bc,
    const float* __restrict__ Wo, const float* __restrict__ Bo,
    float* __restrict__ out,
    unsigned int* __restrict__ cnt)
{
    // Force 1 WG/CU so all 256 WGs are co-resident (spin-sync safety).
    __shared__ char lds_pad[84 * 1024];
    if (blockIdx.x == 0xFFFFFFFFu) lds_pad[threadIdx.x] = 1;

    const int tid  = threadIdx.x;
    const int wv   = tid >> 6;            // wave 0..3 = N-tile
    const int lane = tid & 63;
    const int n    = lane & 15;           // B-frag col / D col (gate row in tile)
    const int kg   = lane >> 4;           // k-group 0..3
    const int wg   = blockIdx.x & 31;     // WG within cluster
    const int cl   = blockIdx.x >> 5;     // cluster 0..7

    // Gate-row mapping (rows interleaved jj*4+g so one wave holds all 4 gates
    // for 4 h-indices):
    const int jj = (wv << 2) + (n >> 2);          // 0..15 within WG
    const int j  = (wg << 4) + jj;                // 0..511 global h index
    const int g  = n & 3;                         // 0=f 1=i 2=c 3=o

    const float* Wg = (g == 0) ? Wf : (g == 1) ? Wi : (g == 2) ? Wc : Wo;
    const float* Bg = (g == 0) ? Bf : (g == 1) ? Bi : (g == 2) ? Bc : Bo;

    // A-operand batch row for this lane (M = lane&15; clamp 8..15 -> 7, rows
    // 8..15 of D are computed on duplicate data and never read).
    const int m_a   = (n < 8) ? n : 7;
    const int bglob = cl * 8 + m_a;

    // ---- prologue: static B-fragments (weights, bf16) into VGPRs ----
    bf16x8 bfrag[32];
    {
        const float* wrow = Wg + (size_t)j * (NH + NI);
        #pragma unroll
        for (int kb = 0; kb < 32; ++kb) {
            const float* p = wrow + kb * 32 + kg * 8;
            float4 w0 = *(const float4*)(p);
            float4 w1 = *(const float4*)(p + 4);
            bfrag[kb] = pack8(w0, w1);
        }
    }
    const float bias_v = Bg[j];

    // ---- C state in registers of "active" lanes ----
    const bool active = (g == 0) && (kg < 2);     // 8 lanes/wave, 4 regs each
    float Cst[4];
    #pragma unroll
    for (int r = 0; r < 4; ++r)
        Cst[r] = active ? c0[(size_t)(cl * 8 + kg * 4 + r) * NH + j] : 0.0f;

    unsigned int* mycnt = cnt + cl * 64;          // 256B-strided counters

    for (int t = 0; t < NT; ++t) {
        // -- x fragments: issue loads + cvt BEFORE the spin (latency hides) --
        const float* xrow = x + ((size_t)t * NB + bglob) * NI;
        bf16x8 xfrag[16];
        #pragma unroll
        for (int q = 0; q < 16; ++q) {
            const float* p = xrow + q * 32 + kg * 8;
            float4 v0 = *(const float4*)(p);
            float4 v1 = *(const float4*)(p + 4);
            xfrag[q] = pack8(v0, v1);
        }

        // -- cluster barrier: wait until all 32 WGs finished step t-1 --
        if (t > 0) {
            const unsigned int target = 32u * (unsigned int)t;
            int guard = 0;
            while (__hip_atomic_load(mycnt, __ATOMIC_ACQUIRE,
                                     __HIP_MEMORY_SCOPE_AGENT) < target) {
                __builtin_amdgcn_s_sleep(1);
                if (++guard > (1 << 24)) break;   // hang safety
            }
        }

        // -- h loads (fp32, from out[t-1], or h0 at t=0) --
        const float* hrow = (t == 0)
            ? (h0 + (size_t)bglob * NH)
            : (out + ((size_t)(t - 1) * NB + bglob) * NH);
        float4 hv[32];
        #pragma unroll
        for (int q = 0; q < 16; ++q) {
            const float* p = hrow + q * 32 + kg * 8;
            hv[2 * q]     = *(const float4*)(p);
            hv[2 * q + 1] = *(const float4*)(p + 4);
        }

        // -- 32 MFMAs, 4 accumulator chains. x-part first (h still in flight)
        f32x4 a0 = {bias_v, bias_v, bias_v, bias_v};
        f32x4 a1 = {0.f, 0.f, 0.f, 0.f};
        f32x4 a2 = {0.f, 0.f, 0.f, 0.f};
        f32x4 a3 = {0.f, 0.f, 0.f, 0.f};
        #pragma unroll
        for (int q = 0; q < 16; q += 4) {
            a0 = __builtin_amdgcn_mfma_f32_16x16x32_bf16(xfrag[q],     bfrag[16 + q],     a0, 0, 0, 0);
            a1 = __builtin_amdgcn_mfma_f32_16x16x32_bf16(xfrag[q + 1], bfrag[16 + q + 1], a1, 0, 0, 0);
            a2 = __builtin_amdgcn_mfma_f32_16x16x32_bf16(xfrag[q + 2], bfrag[16 + q + 2], a2, 0, 0, 0);
            a3 = __builtin_amdgcn_mfma_f32_16x16x32_bf16(xfrag[q + 3], bfrag[16 + q + 3], a3, 0, 0, 0);
        }
        #pragma unroll
        for (int q = 0; q < 16; q += 4) {
            a0 = __builtin_amdgcn_mfma_f32_16x16x32_bf16(pack8(hv[2*q],     hv[2*q + 1]), bfrag[q],     a0, 0, 0, 0);
            a1 = __builtin_amdgcn_mfma_f32_16x16x32_bf16(pack8(hv[2*q + 2], hv[2*q + 3]), bfrag[q + 1], a1, 0, 0, 0);
            a2 = __builtin_amdgcn_mfma_f32_16x16x32_bf16(pack8(hv[2*q + 4], hv[2*q + 5]), bfrag[q + 2], a2, 0, 0, 0);
            a3 = __builtin_amdgcn_mfma_f32_16x16x32_bf16(pack8(hv[2*q + 6], hv[2*q + 7]), bfrag[q + 3], a3, 0, 0, 0);
        }
        f32x4 acc = (a0 + a1) + (a2 + a3);

        // -- gather f/i/c/o within 4-lane groups, elementwise, store h --
        #pragma unroll
        for (int r = 0; r < 4; ++r) {
            float fv = acc[r];
            float iv = __shfl_xor(fv, 1);
            float gv = __shfl_xor(fv, 2);
            float ov = __shfl_xor(fv, 3);
            if (active) {
                float ft = sigm(fv);
                float it = sigm(iv);
                float gt = tanh_f(gv);
                float ot = sigm(ov);
                float Cn = ft * Cst[r] + it * gt;
                Cst[r] = Cn;
                float ht = ot * tanh_f(Cn);
                int m = kg * 4 + r;
                out[((size_t)t * NB + cl * 8 + m) * NH + j] = ht;
            }
        }

        // -- publish step t: fence all lanes' stores, then one release-add --
        __threadfence();
        __syncthreads();
        if (tid == 0)
            __hip_atomic_fetch_add(mycnt, 1u, __ATOMIC_RELEASE,
                                   __HIP_MEMORY_SCOPE_AGENT);
    }
}

extern "C" void kernel_launch(void* const* d_in, const int* in_sizes, int n_in,
                              void* d_out, int out_size, void* d_ws, size_t ws_size,
                              hipStream_t stream) {
    const float* x  = (const float*)d_in[0];
    const float* h0 = (const float*)d_in[1];
    const float* c0 = (const float*)d_in[2];
    const float* Wf = (const float*)d_in[3];
    const float* Bf = (const float*)d_in[4];
    const float* Wi = (const float*)d_in[5];
    const float* Bi = (const float*)d_in[6];
    const float* Wc = (const float*)d_in[7];
    const float* Bc = (const float*)d_in[8];
    const float* Wo = (const float*)d_in[9];
    const float* Bo = (const float*)d_in[10];
    float* out = (float*)d_out;
    unsigned int* cnt = (unsigned int*)d_ws;

    // Zero the barrier counters every launch (d_ws is NOT re-poisoned between
    // graph replays; monotonic counters must restart at 0).
    hipMemsetAsync(d_ws, 0, 4096, stream);

    lstm_fused<<<dim3(256), dim3(256), 0, stream>>>(
        x, h0, c0, Wf, Bf, Wi, Bi, Wc, Bc, Wo, Bo, out, cnt);
}

// Round 2
// 6645.516 us; speedup vs baseline: 6.0401x; 6.0401x over previous
//
#include <hip/hip_runtime.h>
#include <hip/hip_bf16.h>

// LSTM: L=1024, B=64, I=512, H=512, fp32 in/out.
// Persistent kernel: 8 clusters x 32 WGs (cluster c = XCD c via blockIdx&7).
// Cluster = 8 batches; WG = 16 h-idx (64 gate rows). Weights live in VGPRs as
// MFMA B-fragments. h exchanged via bf16 double-buffer in d_ws using RELAXED
// agent-scope atomics (per-access sc0/sc1 coherence -> NO L2 inv/wb fences).
// Per-cluster monotonic barrier counter in d_ws, relaxed add + relaxed spin.

typedef __attribute__((ext_vector_type(8))) short bf16x8;
typedef __attribute__((ext_vector_type(4))) float f32x4;

#define NT 1024
#define NB 64
#define NH 512
#define NI 512

#define CNT_BYTES 4096   // 8 counters, 256B apart

__device__ __forceinline__ bf16x8 pack8(float4 a, float4 b) {
    union U2 { __hip_bfloat162 h; unsigned int u; } c0, c1, c2, c3;
    c0.h = __float22bfloat162_rn(make_float2(a.x, a.y));
    c1.h = __float22bfloat162_rn(make_float2(a.z, a.w));
    c2.h = __float22bfloat162_rn(make_float2(b.x, b.y));
    c3.h = __float22bfloat162_rn(make_float2(b.z, b.w));
    union R { bf16x8 v; unsigned int u[4]; } r;
    r.u[0] = c0.u; r.u[1] = c1.u; r.u[2] = c2.u; r.u[3] = c3.u;
    return r.v;
}

__device__ __forceinline__ float sigm(float v) {
    return 1.0f / (1.0f + __expf(-v));
}
__device__ __forceinline__ float tanh_f(float v) {
    float e = __expf(-2.0f * fabsf(v));        // in (0,1], no overflow
    float r = (1.0f - e) / (1.0f + e);
    return copysignf(r, v);
}

__global__ __launch_bounds__(256, 1) void lstm_fused(
    const float* __restrict__ x,
    const float* __restrict__ h0,
    const float* __restrict__ c0,
    const float* __restrict__ Wf, const float* __restrict__ Bf,
    const float* __restrict__ Wi, const float* __restrict__ Bi,
    const float* __restrict__ Wc, const float* __restrict__ Bc,
    const float* __restrict__ Wo, const float* __restrict__ Bo,
    float* __restrict__ out,
    __hip_bfloat16* __restrict__ hx,      // [2][NB][NH] bf16 exchange
    unsigned int* __restrict__ cnt)
{
    const int tid  = threadIdx.x;
    const int wv   = tid >> 6;            // wave 0..3 = N-tile
    const int lane = tid & 63;
    const int n    = lane & 15;           // D col (gate row within tile)
    const int kg   = lane >> 4;           // k-group 0..3
    const int cl   = blockIdx.x & 7;      // cluster == XCD (perf-only mapping)
    const int wg   = blockIdx.x >> 3;     // WG within cluster, 0..31

    const int jj = (wv << 2) + (n >> 2);          // 0..15 within WG
    const int j  = (wg << 4) + jj;                // global h index
    const int g  = n & 3;                         // 0=f 1=i 2=c 3=o

    const float* Wg = (g == 0) ? Wf : (g == 1) ? Wi : (g == 2) ? Wc : Wo;
    const float* Bg = (g == 0) ? Bf : (g == 1) ? Bi : (g == 2) ? Bc : Bo;

    const int m_a   = (n < 8) ? n : 7;            // A-row batch (8..15 dup)
    const int bglob = cl * 8 + m_a;

    // ---- prologue: static B-fragments (weights, bf16) into VGPRs ----
    bf16x8 bfrag[32];
    {
        const float* wrow = Wg + (size_t)j * (NH + NI);
        #pragma unroll
        for (int kb = 0; kb < 32; ++kb) {
            const float* p = wrow + kb * 32 + kg * 8;
            float4 w0 = *(const float4*)(p);
            float4 w1 = *(const float4*)(p + 4);
            bfrag[kb] = pack8(w0, w1);
        }
    }
    const float bias_v = Bg[j];

    // ---- C state in registers of "active" lanes ----
    const bool active = (g == 0) && (kg < 2);     // 8 lanes/wave x 4 regs
    float Cst[4];
    #pragma unroll
    for (int r = 0; r < 4; ++r)
        Cst[r] = active ? c0[(size_t)(cl * 8 + kg * 4 + r) * NH + j] : 0.0f;

    unsigned int* mycnt = cnt + cl * 64;          // 256B-strided counters

    for (int t = 0; t < NT; ++t) {
        // -- x fragments + x-partial MFMAs BEFORE the spin (no dependency) --
        const float* xrow = x + ((size_t)t * NB + bglob) * NI;
        bf16x8 xfrag[16];
        #pragma unroll
        for (int q = 0; q < 16; ++q) {
            const float* p = xrow + q * 32 + kg * 8;
            float4 v0 = *(const float4*)(p);
            float4 v1 = *(const float4*)(p + 4);
            xfrag[q] = pack8(v0, v1);
        }
        f32x4 a0 = {bias_v, bias_v, bias_v, bias_v};
        f32x4 a1 = {0.f, 0.f, 0.f, 0.f};
        f32x4 a2 = {0.f, 0.f, 0.f, 0.f};
        f32x4 a3 = {0.f, 0.f, 0.f, 0.f};
        #pragma unroll
        for (int q = 0; q < 16; q += 4) {
            a0 = __builtin_amdgcn_mfma_f32_16x16x32_bf16(xfrag[q],     bfrag[16 + q],     a0, 0, 0, 0);
            a1 = __builtin_amdgcn_mfma_f32_16x16x32_bf16(xfrag[q + 1], bfrag[16 + q + 1], a1, 0, 0, 0);
            a2 = __builtin_amdgcn_mfma_f32_16x16x32_bf16(xfrag[q + 2], bfrag[16 + q + 2], a2, 0, 0, 0);
            a3 = __builtin_amdgcn_mfma_f32_16x16x32_bf16(xfrag[q + 3], bfrag[16 + q + 3], a3, 0, 0, 0);
        }

        // -- cluster barrier: relaxed spin (NO acquire -> no cache inv) --
        if (t > 0) {
            const unsigned int target = 32u * (unsigned int)t;
            int guard = 0;
            while (__hip_atomic_load(mycnt, __ATOMIC_RELAXED,
                                     __HIP_MEMORY_SCOPE_AGENT) < target) {
                __builtin_amdgcn_s_sleep(1);
                if (++guard > (1 << 22)) break;   // hang safety
            }
        }
        __builtin_amdgcn_sched_barrier(0);        // keep h-loads after spin

        // -- h fragments: bf16 from exchange buffer (sc0 sc1 per-access) --
        bf16x8 hfrag[16];
        if (t == 0) {
            const float* hrow = h0 + (size_t)bglob * NH;
            #pragma unroll
            for (int q = 0; q < 16; ++q) {
                const float* p = hrow + q * 32 + kg * 8;
                float4 v0 = *(const float4*)(p);
                float4 v1 = *(const float4*)(p + 4);
                hfrag[q] = pack8(v0, v1);
            }
        } else {
            const __hip_bfloat16* hrow =
                hx + ((size_t)((t - 1) & 1) * NB + bglob) * NH;
            #pragma unroll
            for (int q = 0; q < 16; ++q) {
                const unsigned long long* p =
                    (const unsigned long long*)(hrow + q * 32 + kg * 8);
                union { bf16x8 v; unsigned long long u[2]; } un;
                un.u[0] = __hip_atomic_load(p,     __ATOMIC_RELAXED,
                                            __HIP_MEMORY_SCOPE_AGENT);
                un.u[1] = __hip_atomic_load(p + 1, __ATOMIC_RELAXED,
                                            __HIP_MEMORY_SCOPE_AGENT);
                hfrag[q] = un.v;
            }
        }

        #pragma unroll
        for (int q = 0; q < 16; q += 4) {
            a0 = __builtin_amdgcn_mfma_f32_16x16x32_bf16(hfrag[q],     bfrag[q],     a0, 0, 0, 0);
            a1 = __builtin_amdgcn_mfma_f32_16x16x32_bf16(hfrag[q + 1], bfrag[q + 1], a1, 0, 0, 0);
            a2 = __builtin_amdgcn_mfma_f32_16x16x32_bf16(hfrag[q + 2], bfrag[q + 2], a2, 0, 0, 0);
            a3 = __builtin_amdgcn_mfma_f32_16x16x32_bf16(hfrag[q + 3], bfrag[q + 3], a3, 0, 0, 0);
        }
        f32x4 acc = (a0 + a1) + (a2 + a3);

        // -- gather f/i/c/o within 4-lane groups, elementwise, store h --
        __hip_bfloat16* hxout = hx + (size_t)(t & 1) * NB * NH;
        #pragma unroll
        for (int r = 0; r < 4; ++r) {
            float fv = acc[r];
            float iv = __shfl_xor(fv, 1);
            float gv = __shfl_xor(fv, 2);
            float ov = __shfl_xor(fv, 3);
            if (active) {
                float ft = sigm(fv);
                float it = sigm(iv);
                float gt = tanh_f(gv);
                float ot = sigm(ov);
                float Cn = ft * Cst[r] + it * gt;
                Cst[r] = Cn;
                float ht = ot * tanh_f(Cn);
                int m = kg * 4 + r;                       // batch within cluster
                out[((size_t)t * NB + cl * 8 + m) * NH + j] = ht;
                // bf16 exchange store, per-access agent coherence:
                __hip_bfloat16 hb = __float2bfloat16(ht);
                unsigned int us = *(unsigned short*)&hb;
                const __hip_bfloat16* ep = hxout + (size_t)(cl * 8 + m) * NH + j;
                asm volatile("global_store_short %0, %1, off sc0 sc1"
                             :: "v"(ep), "v"(us) : "memory");
            }
        }

        // -- publish step t: drain this wave's stores, WG-sync, one add --
        asm volatile("s_waitcnt vmcnt(0)" ::: "memory");
        __syncthreads();
        if (tid == 0)
            __hip_atomic_fetch_add(mycnt, 1u, __ATOMIC_RELAXED,
                                   __HIP_MEMORY_SCOPE_AGENT);
    }
}

extern "C" void kernel_launch(void* const* d_in, const int* in_sizes, int n_in,
                              void* d_out, int out_size, void* d_ws, size_t ws_size,
                              hipStream_t stream) {
    const float* x  = (const float*)d_in[0];
    const float* h0 = (const float*)d_in[1];
    const float* c0 = (const float*)d_in[2];
    const float* Wf = (const float*)d_in[3];
    const float* Bf = (const float*)d_in[4];
    const float* Wi = (const float*)d_in[5];
    const float* Bi = (const float*)d_in[6];
    const float* Wc = (const float*)d_in[7];
    const float* Bc = (const float*)d_in[8];
    const float* Wo = (const float*)d_in[9];
    const float* Bo = (const float*)d_in[10];
    float* out = (float*)d_out;

    unsigned int*   cnt = (unsigned int*)d_ws;
    __hip_bfloat16* hx  = (__hip_bfloat16*)((char*)d_ws + CNT_BYTES);

    // Zero the barrier counters every launch (monotonic counters must restart
    // at 0; d_ws is not re-poisoned between graph replays).
    hipMemsetAsync(d_ws, 0, CNT_BYTES, stream);

    lstm_fused<<<dim3(256), dim3(256), 0, stream>>>(
        x, h0, c0, Wf, Bf, Wi, Bi, Wc, Bc, Wo, Bo, out, hx, cnt);
}